// Round 1
// baseline (416.060 us; speedup 1.0000x reference)
//
#include <hip/hip_runtime.h>
#include <math.h>

// Problem constants (from reference): B=32, I=2048, O=32, C=16, U=32
#define B_   32
#define I_   2048
#define O_   32
#define C_   16
#define U_   32
#define NCOL (O_ * U_)        // 1024 output columns (o,u)
#define TI   4                // i-values per block -> 512 blocks

// Key insight: softmax over the singleton axis of b_log is identically 1,
// so the routing iterations are no-ops. Output = squash(sum_{i,c} x*w).
//
// s[b, o*32+u] = sum_{i,c} x[b,i,c] * w[i,o,c,u]
// Each thread owns 4 consecutive u for one o (col = 4*tid) and ALL 32 b's,
// so every w element is fetched from HBM exactly once (float4, coalesced).
// x chunk for the block's TI i's is staged in LDS (stride-33 pad: conflict-
// free writes, broadcast reads). Partials combined via fp32 atomics into
// d_out (128 KB, L2-resident), squash applied in-place afterwards.

__global__ __launch_bounds__(256, 2) void caps_main(const float* __restrict__ x,
                                                    const float* __restrict__ w,
                                                    float* __restrict__ out) {
    __shared__ float xs[TI * C_ * 33];   // xs[rem*33 + b], rem = il*C + c
    const int tid = threadIdx.x;
    const int i0 = blockIdx.x * TI;

    // Stage x[:, i0:i0+TI, :] -> LDS. Consecutive lanes read consecutive
    // global floats (coalesced); LDS bank = (rem + b) % 32 -> conflict-free.
    for (int k = tid; k < B_ * TI * C_; k += 256) {
        int b   = k >> 6;     // / (TI*C_) == 64
        int rem = k & 63;
        xs[rem * 33 + b] = x[(size_t)b * (I_ * C_) + (size_t)i0 * C_ + rem];
    }
    __syncthreads();

    const int o  = tid >> 3;
    const int u4 = (tid & 7) << 2;
    const float* wp = w + (size_t)i0 * (O_ * C_ * U_) + o * (C_ * U_) + u4;

    float4 acc[B_];
#pragma unroll
    for (int b = 0; b < B_; ++b) acc[b] = make_float4(0.f, 0.f, 0.f, 0.f);

    for (int il = 0; il < TI; ++il) {
        const float* wpi = wp + (size_t)il * (O_ * C_ * U_);
        const float* xr  = &xs[il * C_ * 33];
#pragma unroll
        for (int c = 0; c < C_; ++c) {
            float4 wv = *(const float4*)(wpi + c * U_);  // coalesced 16B/lane
            const float* xc = xr + c * 33;
#pragma unroll
            for (int b = 0; b < B_; ++b) {
                float xb = xc[b];                        // LDS broadcast
                acc[b].x = fmaf(xb, wv.x, acc[b].x);
                acc[b].y = fmaf(xb, wv.y, acc[b].y);
                acc[b].z = fmaf(xb, wv.z, acc[b].z);
                acc[b].w = fmaf(xb, wv.w, acc[b].w);
            }
        }
    }

    // col = o*32 + u4 = 4*tid ; out[b*1024 + col]
    float* op = out + o * U_ + u4;
#pragma unroll
    for (int b = 0; b < B_; ++b) {
        float* p = op + (size_t)b * NCOL;
        atomicAdd(p + 0, acc[b].x);
        atomicAdd(p + 1, acc[b].y);
        atomicAdd(p + 2, acc[b].z);
        atomicAdd(p + 3, acc[b].w);
    }
}

// In-place squash over the u (last) dimension: v = s * n / (1 + n^2).
// 32 consecutive threads = one (b,o) group; shuffle reduction of sum(s^2).
__global__ void caps_squash(float* __restrict__ out) {
    int t = blockIdx.x * 256 + threadIdx.x;
    float s  = out[t];
    float ss = s * s;
    ss += __shfl_xor(ss, 1);
    ss += __shfl_xor(ss, 2);
    ss += __shfl_xor(ss, 4);
    ss += __shfl_xor(ss, 8);
    ss += __shfl_xor(ss, 16);
    float n = sqrtf(ss);
    out[t] = s * n / (1.0f + ss);
}

extern "C" void kernel_launch(void* const* d_in, const int* in_sizes, int n_in,
                              void* d_out, int out_size, void* d_ws, size_t ws_size,
                              hipStream_t stream) {
    const float* x = (const float*)d_in[0];   // [B, I, C]
    const float* w = (const float*)d_in[1];   // [I, O, C, U]
    float* out = (float*)d_out;               // [B, O, 1, U] = 32768 floats

    // d_out is poisoned 0xAA before every launch; atomics need zeros.
    hipMemsetAsync(out, 0, (size_t)B_ * NCOL * sizeof(float), stream);
    caps_main<<<I_ / TI, 256, 0, stream>>>(x, w, out);
    caps_squash<<<(B_ * NCOL) / 256, 256, 0, stream>>>(out);
}

// Round 2
// 223.750 us; speedup vs baseline: 1.8595x; 1.8595x over previous
//
#include <hip/hip_runtime.h>
#include <math.h>

// Problem constants (from reference): B=32, I=2048, O=32, C=16, U=32
#define B_   32
#define I_   2048
#define O_   32
#define C_   16
#define U_   32
#define NCOL (O_ * U_)        // 1024 output columns (o,u)
#define TI   4                // i-values per block -> 512 blocks
#define NBLK (I_ / TI)        // 512 partials
#define SLICE (B_ * NCOL)     // 32768 floats per partial slice

// softmax over the singleton axis of b_log is identically 1 -> routing
// iterations are no-ops. Output = squash(sum_{i,c} x[b,i,c] * w[i,o,c,u]).
//
// R2: atomics killed the R1 kernel (16.7M device-scope RMWs -> 256 MB
// WRITE_SIZE, VALUBusy 5.9%). Now: K1 writes per-block partials to d_ws
// (contention-free, coalesced), K2 reduces 512 partials + fused squash.

__global__ __launch_bounds__(256, 2) void caps_partial(const float* __restrict__ x,
                                                       const float* __restrict__ w,
                                                       float* __restrict__ ws) {
    __shared__ float xs[TI * C_ * 33];   // xs[rem*33 + b], rem = il*C + c
    const int tid = threadIdx.x;
    const int i0 = blockIdx.x * TI;

    // Stage x[:, i0:i0+TI, :] -> LDS (coalesced global, conflict-free LDS).
    for (int k = tid; k < B_ * TI * C_; k += 256) {
        int b   = k >> 6;     // / (TI*C_) == 64
        int rem = k & 63;
        xs[rem * 33 + b] = x[(size_t)b * (I_ * C_) + (size_t)i0 * C_ + rem];
    }
    __syncthreads();

    const int o  = tid >> 3;
    const int u4 = (tid & 7) << 2;
    const float* wp = w + (size_t)i0 * (O_ * C_ * U_) + o * (C_ * U_) + u4;

    float4 acc[B_];
#pragma unroll
    for (int b = 0; b < B_; ++b) acc[b] = make_float4(0.f, 0.f, 0.f, 0.f);

    for (int il = 0; il < TI; ++il) {
        const float* wpi = wp + (size_t)il * (O_ * C_ * U_);
        const float* xr  = &xs[il * C_ * 33];
        // Load the 16 independent w float4s first (deep MLP), then FMA.
        float4 wv[C_];
#pragma unroll
        for (int c = 0; c < C_; ++c) wv[c] = *(const float4*)(wpi + c * U_);
#pragma unroll
        for (int c = 0; c < C_; ++c) {
            const float* xc = xr + c * 33;
#pragma unroll
            for (int b = 0; b < B_; ++b) {
                float xb = xc[b];                        // LDS broadcast
                acc[b].x = fmaf(xb, wv[c].x, acc[b].x);
                acc[b].y = fmaf(xb, wv[c].y, acc[b].y);
                acc[b].z = fmaf(xb, wv[c].z, acc[b].z);
                acc[b].w = fmaf(xb, wv[c].w, acc[b].w);
            }
        }
    }

    // Private partial slice: ws[blk][b][col], col = 4*tid. Coalesced.
    float* op = ws + (size_t)blockIdx.x * SLICE + u4 + o * U_;
#pragma unroll
    for (int b = 0; b < B_; ++b)
        *(float4*)(op + (size_t)b * NCOL) = acc[b];
}

// Sum 512 partials per output element, then squash over the u dim
// (32 consecutive threads = one (b,o) group; shuffle reduction).
__global__ void caps_reduce_squash(const float* __restrict__ ws,
                                   float* __restrict__ out) {
    int t = blockIdx.x * 256 + threadIdx.x;   // t in [0, 32768)
    float s = 0.f;
#pragma unroll 8
    for (int p = 0; p < NBLK; ++p)
        s += ws[(size_t)p * SLICE + t];
    float ss = s * s;
    ss += __shfl_xor(ss, 1);
    ss += __shfl_xor(ss, 2);
    ss += __shfl_xor(ss, 4);
    ss += __shfl_xor(ss, 8);
    ss += __shfl_xor(ss, 16);
    float n = sqrtf(ss);
    out[t] = s * n / (1.0f + ss);
}

// ---------------- fallback (R1 atomic path) if ws too small ----------------
__global__ __launch_bounds__(256, 2) void caps_main_atomic(const float* __restrict__ x,
                                                           const float* __restrict__ w,
                                                           float* __restrict__ out) {
    __shared__ float xs[TI * C_ * 33];
    const int tid = threadIdx.x;
    const int i0 = blockIdx.x * TI;
    for (int k = tid; k < B_ * TI * C_; k += 256) {
        int b = k >> 6, rem = k & 63;
        xs[rem * 33 + b] = x[(size_t)b * (I_ * C_) + (size_t)i0 * C_ + rem];
    }
    __syncthreads();
    const int o = tid >> 3, u4 = (tid & 7) << 2;
    const float* wp = w + (size_t)i0 * (O_ * C_ * U_) + o * (C_ * U_) + u4;
    float4 acc[B_];
#pragma unroll
    for (int b = 0; b < B_; ++b) acc[b] = make_float4(0.f, 0.f, 0.f, 0.f);
    for (int il = 0; il < TI; ++il) {
        const float* wpi = wp + (size_t)il * (O_ * C_ * U_);
        const float* xr = &xs[il * C_ * 33];
#pragma unroll
        for (int c = 0; c < C_; ++c) {
            float4 wv = *(const float4*)(wpi + c * U_);
            const float* xc = xr + c * 33;
#pragma unroll
            for (int b = 0; b < B_; ++b) {
                float xb = xc[b];
                acc[b].x = fmaf(xb, wv.x, acc[b].x);
                acc[b].y = fmaf(xb, wv.y, acc[b].y);
                acc[b].z = fmaf(xb, wv.z, acc[b].z);
                acc[b].w = fmaf(xb, wv.w, acc[b].w);
            }
        }
    }
    float* op = out + o * U_ + u4;
#pragma unroll
    for (int b = 0; b < B_; ++b) {
        float* p = op + (size_t)b * NCOL;
        atomicAdd(p + 0, acc[b].x);
        atomicAdd(p + 1, acc[b].y);
        atomicAdd(p + 2, acc[b].z);
        atomicAdd(p + 3, acc[b].w);
    }
}

__global__ void caps_squash_inplace(float* __restrict__ out) {
    int t = blockIdx.x * 256 + threadIdx.x;
    float s = out[t];
    float ss = s * s;
    ss += __shfl_xor(ss, 1);
    ss += __shfl_xor(ss, 2);
    ss += __shfl_xor(ss, 4);
    ss += __shfl_xor(ss, 8);
    ss += __shfl_xor(ss, 16);
    float n = sqrtf(ss);
    out[t] = s * n / (1.0f + ss);
}

extern "C" void kernel_launch(void* const* d_in, const int* in_sizes, int n_in,
                              void* d_out, int out_size, void* d_ws, size_t ws_size,
                              hipStream_t stream) {
    const float* x = (const float*)d_in[0];   // [B, I, C]
    const float* w = (const float*)d_in[1];   // [I, O, C, U]
    float* out = (float*)d_out;               // [B, O, 1, U] = 32768 floats

    const size_t need = (size_t)NBLK * SLICE * sizeof(float);   // 64 MB
    if (ws_size >= need) {
        float* ws = (float*)d_ws;
        caps_partial<<<NBLK, 256, 0, stream>>>(x, w, ws);
        caps_reduce_squash<<<SLICE / 256, 256, 0, stream>>>(ws, out);
    } else {
        hipMemsetAsync(out, 0, (size_t)SLICE * sizeof(float), stream);
        caps_main_atomic<<<NBLK, 256, 0, stream>>>(x, w, out);
        caps_squash_inplace<<<SLICE / 256, 256, 0, stream>>>(out);
    }
}

// Round 3
// 211.778 us; speedup vs baseline: 1.9646x; 1.0565x over previous
//
#include <hip/hip_runtime.h>
#include <math.h>

// Problem constants (from reference): B=32, I=2048, O=32, C=16, U=32
#define B_   32
#define I_   2048
#define O_   32
#define C_   16
#define U_   32
#define NCOL (O_ * U_)        // 1024 output columns (o,u)
#define TI   4                // i-values per block -> 512 blocks
#define NBLK (I_ / TI)        // 512 partial slices
#define SLICE (B_ * NCOL)     // 32768 floats per partial slice
#define BH   16               // batches per thread (batch split across tid>>8)
#define XS   36               // x LDS stride: mult-of-4 (b128 alignment), small pad

// softmax over the singleton axis of b_log is identically 1 -> routing
// iterations are no-ops. Output = squash(sum_{i,c} x[b,i,c] * w[i,o,c,u]).
//
// R3: R2's acc[32]f4 = 128 VGPRs forced AGPR shuffling (VGPR_Count=96 < acc
// size) and grid gave only 2 waves/SIMD. Now 512-thread blocks split the
// batch (acc[16]f4 = 64 VGPR, cap 128 @ 4 waves/SIMD), x read from LDS via
// ds_read_b128 (b contiguous, stride 36), w float4 reads duplicated across
// batch halves (L1 hit). K2: 256 blocks, 2 threads/output over p-halves.

__global__ __launch_bounds__(512, 4) void caps_partial(const float* __restrict__ x,
                                                       const float* __restrict__ w,
                                                       float* __restrict__ ws) {
    __shared__ float xs[TI * C_ * XS];   // xs[rem*36 + b], rem = il*C + c
    const int tid = threadIdx.x;         // 0..511
    const int i0 = blockIdx.x * TI;

    // Stage x[:, i0:i0+TI, :]. Global coalesced (lane-fast rem). The stride-36
    // write has bank conflicts but it's only 4 instrs/thread, once.
    for (int k = tid; k < B_ * TI * C_; k += 512) {
        int b   = k >> 6;     // / (TI*C_) == 64
        int rem = k & 63;
        xs[rem * XS + b] = x[(size_t)b * (I_ * C_) + (size_t)i0 * C_ + rem];
    }
    __syncthreads();

    const int bh = tid >> 8;             // batch half: 0 or 1
    const int ct = tid & 255;
    const int o  = ct >> 3;
    const int u4 = (ct & 7) << 2;
    const float* wp = w + (size_t)i0 * (O_ * C_ * U_) + o * (C_ * U_) + u4;

    float4 acc[BH];
#pragma unroll
    for (int b = 0; b < BH; ++b) acc[b] = make_float4(0.f, 0.f, 0.f, 0.f);

    for (int il = 0; il < TI; ++il) {
        const float* wpi = wp + (size_t)il * (O_ * C_ * U_);
        const float* xr  = &xs[il * C_ * XS + bh * BH];
#pragma unroll
        for (int cc = 0; cc < C_; cc += 4) {
            float4 wv[4];
#pragma unroll
            for (int j = 0; j < 4; ++j)
                wv[j] = *(const float4*)(wpi + (cc + j) * U_);   // 16B/lane, coalesced
#pragma unroll
            for (int j = 0; j < 4; ++j) {
                const float4* xv = (const float4*)(xr + (cc + j) * XS);
#pragma unroll
                for (int q = 0; q < 4; ++q) {
                    float4 xq = xv[q];                           // ds_read_b128 broadcast
                    float4* a = &acc[q * 4];
                    a[0].x = fmaf(xq.x, wv[j].x, a[0].x);
                    a[0].y = fmaf(xq.x, wv[j].y, a[0].y);
                    a[0].z = fmaf(xq.x, wv[j].z, a[0].z);
                    a[0].w = fmaf(xq.x, wv[j].w, a[0].w);
                    a[1].x = fmaf(xq.y, wv[j].x, a[1].x);
                    a[1].y = fmaf(xq.y, wv[j].y, a[1].y);
                    a[1].z = fmaf(xq.y, wv[j].z, a[1].z);
                    a[1].w = fmaf(xq.y, wv[j].w, a[1].w);
                    a[2].x = fmaf(xq.z, wv[j].x, a[2].x);
                    a[2].y = fmaf(xq.z, wv[j].y, a[2].y);
                    a[2].z = fmaf(xq.z, wv[j].z, a[2].z);
                    a[2].w = fmaf(xq.z, wv[j].w, a[2].w);
                    a[3].x = fmaf(xq.w, wv[j].x, a[3].x);
                    a[3].y = fmaf(xq.w, wv[j].y, a[3].y);
                    a[3].z = fmaf(xq.w, wv[j].z, a[3].z);
                    a[3].w = fmaf(xq.w, wv[j].w, a[3].w);
                }
            }
        }
    }

    // ws[blk][b][col], col = o*32+u4 = 4*ct. Coalesced float4 stores.
    float* op = ws + (size_t)blockIdx.x * SLICE + (size_t)(bh * BH) * NCOL + o * U_ + u4;
#pragma unroll
    for (int b = 0; b < BH; ++b)
        *(float4*)(op + (size_t)b * NCOL) = acc[b];
}

// Sum 512 partials per output element (2 threads/element over p-halves),
// then squash over u (32 consecutive t = one (b,o) group; shuffle reduce).
__global__ __launch_bounds__(256) void caps_reduce_squash(const float* __restrict__ ws,
                                                          float* __restrict__ out) {
    __shared__ float sh[128];
    const int tl = threadIdx.x & 127;
    const int ph = threadIdx.x >> 7;           // p-half
    const int t  = blockIdx.x * 128 + tl;      // t in [0, 32768)
    const float* p = ws + (size_t)ph * (NBLK / 2) * SLICE + t;
    float s = 0.f;
#pragma unroll 16
    for (int i = 0; i < NBLK / 2; ++i)
        s += p[(size_t)i * SLICE];
    if (ph) sh[tl] = s;
    __syncthreads();
    if (ph == 0) {
        s += sh[tl];
        float ss = s * s;
        ss += __shfl_xor(ss, 1);
        ss += __shfl_xor(ss, 2);
        ss += __shfl_xor(ss, 4);
        ss += __shfl_xor(ss, 8);
        ss += __shfl_xor(ss, 16);
        float n = sqrtf(ss);
        out[t] = s * n / (1.0f + ss);
    }
}

// ---------------- fallback (atomic path) if ws too small ----------------
__global__ __launch_bounds__(256, 2) void caps_main_atomic(const float* __restrict__ x,
                                                           const float* __restrict__ w,
                                                           float* __restrict__ out) {
    __shared__ float xs[TI * C_ * 33];
    const int tid = threadIdx.x;
    const int i0 = blockIdx.x * TI;
    for (int k = tid; k < B_ * TI * C_; k += 256) {
        int b = k >> 6, rem = k & 63;
        xs[rem * 33 + b] = x[(size_t)b * (I_ * C_) + (size_t)i0 * C_ + rem];
    }
    __syncthreads();
    const int o = tid >> 3, u4 = (tid & 7) << 2;
    const float* wp = w + (size_t)i0 * (O_ * C_ * U_) + o * (C_ * U_) + u4;
    float4 acc[B_];
#pragma unroll
    for (int b = 0; b < B_; ++b) acc[b] = make_float4(0.f, 0.f, 0.f, 0.f);
    for (int il = 0; il < TI; ++il) {
        const float* wpi = wp + (size_t)il * (O_ * C_ * U_);
        const float* xr = &xs[il * C_ * 33];
#pragma unroll
        for (int c = 0; c < C_; ++c) {
            float4 wv = *(const float4*)(wpi + c * U_);
            const float* xc = xr + c * 33;
#pragma unroll
            for (int b = 0; b < B_; ++b) {
                float xb = xc[b];
                acc[b].x = fmaf(xb, wv.x, acc[b].x);
                acc[b].y = fmaf(xb, wv.y, acc[b].y);
                acc[b].z = fmaf(xb, wv.z, acc[b].z);
                acc[b].w = fmaf(xb, wv.w, acc[b].w);
            }
        }
    }
    float* op = out + o * U_ + u4;
#pragma unroll
    for (int b = 0; b < B_; ++b) {
        float* p = op + (size_t)b * NCOL;
        atomicAdd(p + 0, acc[b].x);
        atomicAdd(p + 1, acc[b].y);
        atomicAdd(p + 2, acc[b].z);
        atomicAdd(p + 3, acc[b].w);
    }
}

__global__ void caps_squash_inplace(float* __restrict__ out) {
    int t = blockIdx.x * 256 + threadIdx.x;
    float s = out[t];
    float ss = s * s;
    ss += __shfl_xor(ss, 1);
    ss += __shfl_xor(ss, 2);
    ss += __shfl_xor(ss, 4);
    ss += __shfl_xor(ss, 8);
    ss += __shfl_xor(ss, 16);
    float n = sqrtf(ss);
    out[t] = s * n / (1.0f + ss);
}

extern "C" void kernel_launch(void* const* d_in, const int* in_sizes, int n_in,
                              void* d_out, int out_size, void* d_ws, size_t ws_size,
                              hipStream_t stream) {
    const float* x = (const float*)d_in[0];   // [B, I, C]
    const float* w = (const float*)d_in[1];   // [I, O, C, U]
    float* out = (float*)d_out;               // [B, O, 1, U] = 32768 floats

    const size_t need = (size_t)NBLK * SLICE * sizeof(float);   // 64 MB
    if (ws_size >= need) {
        float* ws = (float*)d_ws;
        caps_partial<<<NBLK, 512, 0, stream>>>(x, w, ws);
        caps_reduce_squash<<<SLICE / 128, 256, 0, stream>>>(ws, out);
    } else {
        hipMemsetAsync(out, 0, (size_t)SLICE * sizeof(float), stream);
        caps_main_atomic<<<I_ / TI, 256, 0, stream>>>(x, w, out);
        caps_squash_inplace<<<SLICE / 256, 256, 0, stream>>>(out);
    }
}